// Round 1
// baseline (124.301 us; speedup 1.0000x reference)
//
#include <hip/hip_runtime.h>
#include <cstdint>
#include <cstddef>

// GraphConvSparse: out = relu(adj @ (x @ W)), adj = dense 0/1 symmetric
// adjacency built from edge_index with SET semantics (dups count once).
//
// N=16384, E=524288, D=128.
// d_ws layout: [0, 32MiB) adjacency bitmask (N rows x 512 u32 words)
//              [32MiB, 40MiB) h = x @ W  (N x 128 fp32)

constexpr int NN  = 16384;
constexpr int D   = 128;
constexpr int WPR = NN / 32;            // 512 mask words per row
constexpr size_t MASK_BYTES = (size_t)NN * (NN / 8);   // 32 MiB

// ---------------- kernel 1: build adjacency bitmask ----------------
__global__ __launch_bounds__(256) void build_mask_kernel(
    const int* __restrict__ ei, int E, unsigned int* __restrict__ mask) {
    int e = blockIdx.x * 256 + threadIdx.x;
    if (e >= E) return;
    unsigned int u = (unsigned int)ei[e];        // row 0 of (2,E)
    unsigned int v = (unsigned int)ei[E + e];    // row 1 of (2,E)
    unsigned int i1 = u * NN + v;                // < 2^28, fits u32
    unsigned int i2 = v * NN + u;
    atomicOr(&mask[i1 >> 5], 1u << (i1 & 31));
    atomicOr(&mask[i2 >> 5], 1u << (i2 & 31));
}

// ---------------- kernel 2: h = x @ W (fp32) ----------------
// 64x64 output tile per block, 256 threads, 4x4 register tile/thread.
__global__ __launch_bounds__(256) void gemm_kernel(
    const float* __restrict__ x, const float* __restrict__ w,
    float* __restrict__ h) {
    __shared__ float xt[D][64];   // x tile, transposed [k][row] : 32 KB
    __shared__ float wl[D][64];   // w tile, natural    [k][col] : 32 KB
    const int tid  = threadIdx.x;
    const int rb   = blockIdx.x >> 1;     // 256 row-blocks
    const int cb   = blockIdx.x & 1;      // 2 col-blocks
    const int row0 = rb * 64, col0 = cb * 64;

    // stage x transposed: 64 rows x 128 k
    for (int i = tid; i < 64 * (D / 4); i += 256) {
        int r = i >> 5, k4 = i & 31;
        float4 xv = *(const float4*)&x[(size_t)(row0 + r) * D + (k4 << 2)];
        xt[(k4 << 2) + 0][r] = xv.x;
        xt[(k4 << 2) + 1][r] = xv.y;
        xt[(k4 << 2) + 2][r] = xv.z;
        xt[(k4 << 2) + 3][r] = xv.w;
    }
    // stage w tile: 128 k x 64 cols
    for (int i = tid; i < D * (64 / 4); i += 256) {
        int k = i >> 4, c4 = i & 15;
        *(float4*)&wl[k][c4 << 2] =
            *(const float4*)&w[(size_t)k * D + col0 + (c4 << 2)];
    }
    __syncthreads();

    const int cg = tid & 15, rg = tid >> 4;
    const int c0 = cg << 2, r0 = rg << 2;
    float acc[4][4] = {};
    #pragma unroll 4
    for (int k = 0; k < D; ++k) {
        float4 xv = *(float4*)&xt[k][r0];
        float4 wv = *(float4*)&wl[k][c0];
        const float xr[4] = {xv.x, xv.y, xv.z, xv.w};
        const float wc[4] = {wv.x, wv.y, wv.z, wv.w};
        #pragma unroll
        for (int r = 0; r < 4; ++r)
            #pragma unroll
            for (int c = 0; c < 4; ++c)
                acc[r][c] = fmaf(xr[r], wc[c], acc[r][c]);
    }
    #pragma unroll
    for (int r = 0; r < 4; ++r) {
        float4 v = make_float4(acc[r][0], acc[r][1], acc[r][2], acc[r][3]);
        *(float4*)&h[(size_t)(row0 + r0 + r) * D + col0 + c0] = v;
    }
}

// ---------------- kernel 3: out[i] = relu(sum_{j in adj[i]} h[j]) ----------------
// one block (128 threads) per row; thread t owns output dim t.
__global__ __launch_bounds__(128) void agg_kernel(
    const unsigned int* __restrict__ mask, const float* __restrict__ h,
    float* __restrict__ out) {
    __shared__ int cnt;
    __shared__ int list[2048];          // max degree ~120 expected; 2048 is very safe
    const int row = blockIdx.x, tid = threadIdx.x;
    if (tid == 0) cnt = 0;
    __syncthreads();

    const unsigned int* mrow = mask + (size_t)row * WPR;
    for (int wi = tid; wi < WPR; wi += 128) {
        unsigned int m = mrow[wi];
        while (m) {
            int b = __builtin_ctz(m);
            m &= m - 1;
            int p = atomicAdd(&cnt, 1);
            if (p < 2048) list[p] = (wi << 5) + b;
        }
    }
    __syncthreads();

    int n = cnt; if (n > 2048) n = 2048;
    float acc = 0.f;
    int i = 0;
    for (; i + 4 <= n; i += 4) {
        int j0 = list[i], j1 = list[i + 1], j2 = list[i + 2], j3 = list[i + 3];
        float a0 = h[(size_t)j0 * D + tid];
        float a1 = h[(size_t)j1 * D + tid];
        float a2 = h[(size_t)j2 * D + tid];
        float a3 = h[(size_t)j3 * D + tid];
        acc += a0; acc += a1; acc += a2; acc += a3;
    }
    for (; i < n; ++i) acc += h[(size_t)list[i] * D + tid];

    out[(size_t)row * D + tid] = fmaxf(acc, 0.f);
}

extern "C" void kernel_launch(void* const* d_in, const int* in_sizes, int n_in,
                              void* d_out, int out_size, void* d_ws, size_t ws_size,
                              hipStream_t stream) {
    const float* x  = (const float*)d_in[0];
    const int*   ei = (const int*)d_in[1];     // (2,E) int (harness converts integer inputs)
    const float* w  = (const float*)d_in[3];   // d_in[2] = num_nodes scalar (N fixed)
    float* out = (float*)d_out;

    unsigned int* mask = (unsigned int*)d_ws;
    float* h = (float*)((char*)d_ws + MASK_BYTES);

    const int E = in_sizes[1] / 2;

    // zero the adjacency bitmask every call (ws is not re-poisoned/zeroed)
    hipMemsetAsync(mask, 0, MASK_BYTES, stream);

    build_mask_kernel<<<(E + 255) / 256, 256, 0, stream>>>(ei, E, mask);
    gemm_kernel<<<512, 256, 0, stream>>>(x, w, h);
    agg_kernel<<<NN, 128, 0, stream>>>(mask, h, out);
}